// Round 11
// baseline (292.079 us; speedup 1.0000x reference)
//
#include <hip/hip_runtime.h>
#include <hip/hip_bf16.h>

using bf16 = __hip_bfloat16;
typedef __attribute__((ext_vector_type(8))) short bf16x8;
typedef __attribute__((ext_vector_type(4))) float f32x4;
typedef __attribute__((ext_vector_type(16))) float f32x16;
typedef __attribute__((ext_vector_type(4))) unsigned int u32x4;

constexpr int Bz  = 2;
constexpr int SEQ = 2048;
constexpr int DM  = 2048;
constexpr int H   = 16;
constexpr int HD  = 128;
constexpr long MROWS = (long)Bz * SEQ;   // 4096
constexpr int EQ  = 3 * DM;              // 6144
// 1/sqrt(128) * log2(e): fold softmax base-2 conversion into Q scaling
constexpr float QSCALE_L2E = 0.12751743427795914f;

__device__ __forceinline__ float bf2f(bf16 x) { return __bfloat162float(x); }
__device__ __forceinline__ bf16  f2bf(float x) { return __float2bfloat16(x); }

__device__ __forceinline__ float fexp2(float x) {
  float r;
  asm("v_exp_f32 %0, %1" : "=v"(r) : "v"(x));
  return r;
}

template <int N>
__device__ __forceinline__ void waitvm() {
  asm volatile("s_waitcnt vmcnt(%0)" ::"n"(N) : "memory");
}

__device__ __forceinline__ void gl_lds16(const void* g, void* l) {
  __builtin_amdgcn_global_load_lds(
      (const __attribute__((address_space(1))) unsigned int*)g,
      (__attribute__((address_space(3))) unsigned int*)l, 16, 0, 0);
}

// ---------------- merged fp32 -> bf16 converts ----------------
constexpr long NX = MROWS * DM;          // 8388608
constexpr long NW1 = (long)EQ * DM;      // 12582912
constexpr long NW2 = (long)DM * DM;      // 4194304
__global__ void prep_bf16(const float* __restrict__ x, const float* __restrict__ w1,
                          const float* __restrict__ w2, bf16* __restrict__ xb,
                          bf16* __restrict__ w1b, bf16* __restrict__ w2b) {
  long i = ((long)blockIdx.x * 256 + threadIdx.x) * 4;
  const float* src;
  bf16* dst;
  long off;
  if (i < NX) { src = x; dst = xb; off = i; }
  else if (i < NX + NW1) { src = w1; dst = w1b; off = i - NX; }
  else { src = w2; dst = w2b; off = i - NX - NW1; }
  float4 v = *(const float4*)(src + off);
  bf16 tmp[4] = {f2bf(v.x), f2bf(v.y), f2bf(v.z), f2bf(v.w)};
  *(uint2*)(dst + off) = *(uint2*)tmp;
}

// ---------------- RoPE table ----------------
__global__ void rope_table(float* __restrict__ ct, float* __restrict__ st) {
  int idx = blockIdx.x * 256 + threadIdx.x;
  if (idx >= SEQ * 64) return;
  int j = idx & 63, n = idx >> 6;
  double inv = exp(-(double)j / 64.0 * 9.210340371976184); // 10000^{-j/64}
  double a = (double)n * inv;
  ct[idx] = (float)cos(a);
  st[idx] = (float)sin(a);
}

// ============== GEMM1: 128x384, single-buffer LDS (64KB) -> 2 blocks/CU ==============
// 8 waves (2M x 4N), R9 16x16 frag mapping (0-conflict reads). Per K-tile:
// {stage all 8 chunks -> vmcnt(0) -> barrier -> A-frags + 3 j-pair phases of 16 MFMA
//  -> barrier}. Exposed per-tile drain is covered by the co-resident sibling block.
// Fused epilogue in 3 segment passes (eb = 128 cols x 136 rows, 34.8KB <= 64KB).
__global__ __launch_bounds__(512) void gemm1s(const bf16* __restrict__ A,
                                              const bf16* __restrict__ Bm,
                                              bf16* __restrict__ q_r,
                                              bf16* __restrict__ k_r,
                                              bf16* __restrict__ v_t,
                                              const float* __restrict__ ct,
                                              const float* __restrict__ st) {
  constexpr int KTOT = 2048, BN = 384, NBP = 3, NT = KTOT / 64;
  __shared__ alignas(16) char smem[65536];
  bf16* lsA = (bf16*)smem;                       // 128*64 = 16KB
  bf16* lsB = (bf16*)(smem + 128 * 64 * 2);      // 384*64 = 48KB

  const int nwg = gridDim.x;                     // 512
  const int f = blockIdx.x;
  const int wg = (f & 7) * (nwg >> 3) + (f >> 3);
  const int nbm = (int)(MROWS >> 7);             // 32
  const long am0 = (long)(wg % nbm) * 128;
  const long bn0 = (long)(wg / nbm) * BN;

  const int tid = threadIdx.x;
  const int wv = tid >> 6, ln = tid & 63;
  const int wm = wv & 1, wn = wv >> 1;
  const int fr = ln & 15, kq = ln >> 4;
  const int sr8 = ln >> 3;
  const int ss  = ln & 7;

  f32x4 acc[4][6] = {};

  auto stageA = [&](int t) {
#pragma unroll
    for (int ld = 0; ld < 2; ++ld) {
      const int r = ld * 64 + wv * 8 + sr8;
      const int sl = ss ^ (r & 7);
      gl_lds16(A + (am0 + r) * KTOT + t * 64 + sl * 8, lsA + (ld * 64 + wv * 8) * 64);
    }
  };
  auto stageB = [&](int t, int bp) {
#pragma unroll
    for (int ld = 0; ld < 2; ++ld) {
      const int r = bp * 128 + ld * 64 + wv * 8 + sr8;
      const int sl = ss ^ (r & 7);
      gl_lds16(Bm + (bn0 + r) * KTOT + t * 64 + sl * 8,
               lsB + (bp * 128 + ld * 64 + wv * 8) * 64);
    }
  };

  for (int t = 0; t < NT; ++t) {
    stageA(t);
#pragma unroll
    for (int bp = 0; bp < NBP; ++bp) stageB(t, bp);
    waitvm<0>();
    __builtin_amdgcn_s_barrier();

    bf16x8 af[8];
#pragma unroll
    for (int i = 0; i < 4; ++i)
#pragma unroll
      for (int ks = 0; ks < 2; ++ks) {
        const int row = (wm + 2 * i) * 16 + fr;
        const int sl = (ks * 4 + kq) ^ (row & 7);
        af[i * 2 + ks] = *(const bf16x8*)((const char*)lsA + row * 128 + sl * 16);
      }
#pragma unroll
    for (int bp = 0; bp < NBP; ++bp) {
      bf16x8 bq[4];
#pragma unroll
      for (int jj = 0; jj < 2; ++jj)
#pragma unroll
        for (int ks = 0; ks < 2; ++ks) {
          const int row = (wn + 4 * (2 * bp + jj)) * 16 + fr;
          const int sl = (ks * 4 + kq) ^ (row & 7);
          bq[jj * 2 + ks] = *(const bf16x8*)((const char*)lsB + row * 128 + sl * 16);
        }
      __builtin_amdgcn_s_setprio(1);
#pragma unroll
      for (int i = 0; i < 4; ++i)
#pragma unroll
        for (int jj = 0; jj < 2; ++jj)
#pragma unroll
          for (int ks = 0; ks < 2; ++ks)
            acc[i][2 * bp + jj] = __builtin_amdgcn_mfma_f32_16x16x32_bf16(
                af[i * 2 + ks], bq[jj * 2 + ks], acc[i][2 * bp + jj], 0, 0, 0);
      __builtin_amdgcn_s_setprio(0);
    }
    __builtin_amdgcn_s_barrier();   // all reads consumed -> next-tile staging is WAR-safe
  }

  // ---- fused epilogue: 3 passes of one 128-col head segment each
  bf16* eb = (bf16*)smem;                 // 128 cols x 136 rows = 34816 B
  const int bb = (int)(am0 >> 11);
  const int nbase = (int)(am0 & 2047);
#pragma unroll
  for (int p = 0; p < 3; ++p) {
    __syncthreads();                      // prev pass reads done (or K-loop reads, p==0)
#pragma unroll
    for (int i = 0; i < 4; ++i) {
      const int r0 = (wm + 2 * i) * 16 + kq * 4;
#pragma unroll
      for (int jj = 0; jj < 2; ++jj) {
        const int j = 2 * p + jj;
        const int c = wn * 16 + jj * 64 + fr;     // col within segment (global col - 128p)
        bf16 t4[4];
#pragma unroll
        for (int q = 0; q < 4; ++q) t4[q] = f2bf(acc[i][j][q]);
        *(uint2*)(eb + c * 136 + r0) = *(uint2*)t4;
      }
    }
    __syncthreads();
    const int gc = (int)bn0 + p * 128;
    const int seg = gc >> 11;               // 0=Q 1=K 2=V
    const long bh = bb * 16 + ((gc & 2047) >> 7);
    if (seg < 2) {
      bf16* dst = (seg == 0) ? q_r : k_r;
      const float qs = (seg == 0) ? QSCALE_L2E : 1.0f;
      for (int itx = 0; itx < 16; ++itx) {
        const int idx = itx * 512 + tid;
        const int r = idx >> 6, j = idx & 63;
        const int n = nbase + r;
        const float v1 = bf2f(eb[j * 136 + r]);
        const float v2 = bf2f(eb[(j + 64) * 136 + r]);
        const float cc = ct[n * 64 + j], sv = st[n * 64 + j];
        const long ob = (bh * SEQ + n) * HD + j;
        dst[ob]      = f2bf((v1 * cc - v2 * sv) * qs);
        dst[ob + 64] = f2bf((v1 * sv + v2 * cc) * qs);
      }
    } else {
      for (int itx = 0; itx < 4; ++itx) {
        const int idx = itx * 512 + tid;
        const int d = idx >> 4, n8 = (idx & 15) * 8;
        bf16x8 v = *(const bf16x8*)(eb + d * 136 + n8);
        *(bf16x8*)(v_t + (bh * HD + d) * SEQ + nbase + n8) = v;
      }
    }
  }
}

// ============== GEMM2: 64x256, 4 waves, single-buffer LDS (40KB) -> 2 blocks/CU ==============
__global__ __launch_bounds__(256) void gemm2s(const bf16* __restrict__ A,
                                              const bf16* __restrict__ Bm,
                                              float* __restrict__ Cv,
                                              const float* __restrict__ bias) {
  constexpr int KTOT = 2048, BN = 256, NT = KTOT / 64;
  __shared__ alignas(16) char smem[40960];
  bf16* lsA = (bf16*)smem;                       // 64*64 = 8KB
  bf16* lsB = (bf16*)(smem + 64 * 64 * 2);       // 256*64 = 32KB

  const int nwg = gridDim.x;                     // 512
  const int f = blockIdx.x;
  const int wg = (f & 7) * (nwg >> 3) + (f >> 3);
  const int nbm = (int)(MROWS >> 6);             // 64
  const long am0 = (long)(wg % nbm) * 64;
  const long bn0 = (long)(wg / nbm) * BN;

  const int tid = threadIdx.x;
  const int wn = tid >> 6, ln = tid & 63;        // 4 waves, all on N
  const int fr = ln & 15, kq = ln >> 4;
  const int sr8 = tid >> 3;                      // 0..31: rows within 32-row slab
  const int ss  = tid & 7;

  f32x4 acc[4][4] = {};

  auto stageA = [&](int t) {
#pragma unroll
    for (int ld = 0; ld < 2; ++ld) {
      const int r = ld * 32 + sr8;
      const int sl = ss ^ (r & 7);
      gl_lds16(A + (am0 + r) * KTOT + t * 64 + sl * 8, lsA + (ld * 32 + (sr8 & ~7)) * 64);
    }
  };
  auto stageB = [&](int t) {
#pragma unroll
    for (int ld = 0; ld < 8; ++ld) {
      const int r = ld * 32 + sr8;
      const int sl = ss ^ (r & 7);
      gl_lds16(Bm + (bn0 + r) * KTOT + t * 64 + sl * 8, lsB + (ld * 32 + (sr8 & ~7)) * 64);
    }
  };

  for (int t = 0; t < NT; ++t) {
    stageA(t);
    stageB(t);
    waitvm<0>();
    __builtin_amdgcn_s_barrier();

    bf16x8 af[8];
#pragma unroll
    for (int i = 0; i < 4; ++i)
#pragma unroll
      for (int ks = 0; ks < 2; ++ks) {
        const int row = i * 16 + fr;
        const int sl = (ks * 4 + kq) ^ (row & 7);
        af[i * 2 + ks] = *(const bf16x8*)((const char*)lsA + row * 128 + sl * 16);
      }
#pragma unroll
    for (int j = 0; j < 4; ++j) {
      bf16x8 bq[2];
#pragma unroll
      for (int ks = 0; ks < 2; ++ks) {
        const int row = (wn + 4 * j) * 16 + fr;
        const int sl = (ks * 4 + kq) ^ (row & 7);
        bq[ks] = *(const bf16x8*)((const char*)lsB + row * 128 + sl * 16);
      }
      __builtin_amdgcn_s_setprio(1);
#pragma unroll
      for (int i = 0; i < 4; ++i)
#pragma unroll
        for (int ks = 0; ks < 2; ++ks)
          acc[i][j] = __builtin_amdgcn_mfma_f32_16x16x32_bf16(af[i * 2 + ks], bq[ks],
                                                              acc[i][j], 0, 0, 0);
      __builtin_amdgcn_s_setprio(0);
    }
    __builtin_amdgcn_s_barrier();
  }

#pragma unroll
  for (int i = 0; i < 4; ++i) {
    const long row0 = am0 + i * 16 + kq * 4;
#pragma unroll
    for (int j = 0; j < 4; ++j) {
      const long col = bn0 + (wn + 4 * j) * 16 + fr;
      const float bv = bias[col];
#pragma unroll
      for (int q = 0; q < 4; ++q)
        Cv[(row0 + q) * DM + col] = acc[i][j][q] + bv;
    }
  }
}

// ---------------- Flash attention: 8 waves, swapped-QK^T 32x32, defer-max ----------------
__global__ __launch_bounds__(512, 2) void attn_fwd(const bf16* __restrict__ q_r,
                                                   const bf16* __restrict__ k_r,
                                                   const bf16* __restrict__ v_t,
                                                   bf16* __restrict__ ao) {
  __shared__ alignas(16) char lds[69632];

  const int flat = blockIdx.x;                       // 0..255
  const int bh = (flat & 7) * 4 + (flat >> 6);
  const int qt = (flat >> 3) & 7;
  const int b = bh >> 4, h = bh & 15;

  const int wv = threadIdx.x >> 6, ln = threadIdx.x & 63;
  const int lh = ln >> 5;
  const int lq = ln & 31;
  const int q0 = qt * 256 + wv * 32;

  bf16x8 aq[8];
  {
    const char* qbase = (const char*)(q_r + ((long)bh * SEQ + q0 + lq) * HD);
#pragma unroll
    for (int ks = 0; ks < 8; ++ks)
      aq[ks] = *(const bf16x8*)(qbase + ks * 32 + lh * 16);
  }

  f32x16 oacc[4] = {};
  float mrow = -1e30f, lsum = 0.f;

  auto stage = [&](int buf, int t) {
    char* kb = lds + buf * 16384;
    char* vb = lds + 32768 + buf * 16384;
#pragma unroll
    for (int cc = 0; cc < 4; ++cc) {
      const int chunk = wv * 4 + cc;
      if (chunk < 16) {
        const int r = chunk * 4 + (ln >> 4);
        const char* src = (const char*)k_r + ((long)bh * SEQ + t * 64 + r) * 256 +
                          (((ln & 15) ^ (r & 15)) << 4);
        gl_lds16(src, kb + chunk * 1024);
      } else {
        const int c2 = chunk - 16;
        const int r = c2 * 8 + (ln >> 3);
        const char* src = (const char*)v_t + ((long)bh * HD + r) * (SEQ * 2) + t * 128 +
                          (((ln & 7) ^ (r & 7)) << 4);
        gl_lds16(src, vb + c2 * 1024);
      }
    }
  };

  stage(0, 0);
  __syncthreads();

  for (int t = 0; t < SEQ / 64; ++t) {
    const int cur = t & 1;
    if (t + 1 < SEQ / 64) stage(cur ^ 1, t + 1);
    const char* kb = lds + cur * 16384;
    const char* vb = lds + 32768 + cur * 16384;

    f32x16 sacc[2] = {};
    __builtin_amdgcn_s_setprio(1);
#pragma unroll
    for (int kvs = 0; kvs < 2; ++kvs) {
      const int kv = kvs * 32 + lq;
#pragma unroll
      for (int ks = 0; ks < 8; ++ks) {
        bf16x8 kf = *(const bf16x8*)(kb + kv * 256 + ((((ks << 1) | lh) ^ (kv & 15)) << 4));
        sacc[kvs] = __builtin_amdgcn_mfma_f32_32x32x16_bf16(kf, aq[ks], sacc[kvs], 0, 0, 0);
      }
    }
    __builtin_amdgcn_s_setprio(0);

    float mx = sacc[0][0];
#pragma unroll
    for (int r = 1; r < 16; ++r) mx = fmaxf(mx, sacc[0][r]);
#pragma unroll
    for (int r = 0; r < 16; ++r) mx = fmaxf(mx, sacc[1][r]);
    mx = fmaxf(mx, __shfl_xor(mx, 32, 64));

    if (!__all(mx - mrow <= 8.0f)) {
      const float mn = fmaxf(mrow, mx);
      const float scale = fexp2(mrow - mn);
      mrow = mn;
      lsum *= scale;
#pragma unroll
      for (int dt = 0; dt < 4; ++dt) oacc[dt] *= scale;
    }
    float psum = 0.f;
#pragma unroll
    for (int k2 = 0; k2 < 2; ++k2)
#pragma unroll
      for (int r = 0; r < 16; ++r) {
        const float pv = fexp2(sacc[k2][r] - mrow);
        sacc[k2][r] = pv;
        psum += pv;
      }
    psum += __shfl_xor(psum, 32, 64);
    lsum += psum;

    bf16x8 pfrag[4];
#pragma unroll
    for (int k2 = 0; k2 < 2; ++k2) {
      unsigned int pk[8];
#pragma unroll
      for (int i = 0; i < 8; ++i) {
        unsigned int lo = __bfloat16_as_ushort(f2bf(sacc[k2][2 * i]));
        unsigned int hi = __bfloat16_as_ushort(f2bf(sacc[k2][2 * i + 1]));
        pk[i] = lo | (hi << 16);
      }
#pragma unroll
      for (int fb = 0; fb < 2; ++fb) {
        const unsigned int a0 = pk[fb * 4 + 0], a1 = pk[fb * 4 + 1];
        const unsigned int b0 = pk[fb * 4 + 2], b1 = pk[fb * 4 + 3];
        const unsigned int sb0 = __shfl_xor(b0, 32, 64);
        const unsigned int sb1 = __shfl_xor(b1, 32, 64);
        const unsigned int sa0 = __shfl_xor(a0, 32, 64);
        const unsigned int sa1 = __shfl_xor(a1, 32, 64);
        u32x4 wvec;
        wvec.x = lh ? sb0 : a0;
        wvec.y = lh ? sb1 : a1;
        wvec.z = lh ? b0 : sa0;
        wvec.w = lh ? b1 : sa1;
        pfrag[k2 * 2 + fb] = __builtin_bit_cast(bf16x8, wvec);
      }
    }

    __builtin_amdgcn_s_setprio(1);
#pragma unroll
    for (int dt = 0; dt < 4; ++dt) {
      const int d = dt * 32 + lq;
#pragma unroll
      for (int kk = 0; kk < 4; ++kk) {
        bf16x8 vf = *(const bf16x8*)(vb + d * 128 + ((((kk << 1) | lh) ^ (d & 7)) << 4));
        oacc[dt] = __builtin_amdgcn_mfma_f32_32x32x16_bf16(vf, pfrag[kk], oacc[dt], 0, 0, 0);
      }
    }
    __builtin_amdgcn_s_setprio(0);
    __syncthreads();
  }

  const float inv = 1.0f / lsum;
  bf16* ob = (bf16*)lds;
  const int qloc = wv * 32 + lq;
#pragma unroll
  for (int dt = 0; dt < 4; ++dt)
#pragma unroll
    for (int r = 0; r < 16; ++r) {
      const int d = dt * 32 + (r & 3) + 8 * (r >> 2) + 4 * lh;
      ob[qloc * 132 + d] = f2bf(oacc[dt][r] * inv);
    }
#pragma unroll
  for (int it = 0; it < 8; ++it) {
    const int c = it * 64 + ln;
    const int qq = c >> 4, dc = c & 15;
    const char* srcp = (const char*)ob + (wv * 32 + qq) * 264 + dc * 16;
    uint2 v0 = *(const uint2*)srcp;
    uint2 v1 = *(const uint2*)(srcp + 8);
    uint4 outv;
    outv.x = v0.x; outv.y = v0.y; outv.z = v1.x; outv.w = v1.y;
    *(uint4*)((char*)(ao + ((long)b * SEQ + qt * 256 + wv * 32 + qq) * DM + h * 128) + dc * 16) = outv;
  }
}

// ---------------- launch ----------------
extern "C" void kernel_launch(void* const* d_in, const int* in_sizes, int n_in,
                              void* d_out, int out_size, void* d_ws, size_t ws_size,
                              hipStream_t stream) {
  const float* x      = (const float*)d_in[0];
  const float* w_qkv  = (const float*)d_in[1];
  const float* w_proj = (const float*)d_in[2];
  const float* b_proj = (const float*)d_in[3];

  char* ws = (char*)d_ws;
  size_t off = 0;
  auto alloc = [&](size_t bytes) {
    void* p = ws + off;
    off += (bytes + 255) & ~(size_t)255;
    return p;
  };
  bf16* xb     = (bf16*)alloc((size_t)MROWS * DM * 2);
  bf16* wqkvb  = (bf16*)alloc((size_t)EQ * DM * 2);
  bf16* wprojb = (bf16*)alloc((size_t)DM * DM * 2);
  bf16* q_r    = (bf16*)alloc((size_t)Bz * H * SEQ * HD * 2);
  bf16* k_r    = (bf16*)alloc((size_t)Bz * H * SEQ * HD * 2);
  bf16* v_t    = (bf16*)alloc((size_t)Bz * H * SEQ * HD * 2);
  bf16* aob    = (bf16*)alloc((size_t)MROWS * DM * 2);
  float* ct    = (float*)alloc((size_t)SEQ * 64 * 4);
  float* st    = (float*)alloc((size_t)SEQ * 64 * 4);

  prep_bf16<<<(int)((NX + NW1 + NW2) / 4 / 256), 256, 0, stream>>>(
      x, w_qkv, w_proj, xb, wqkvb, wprojb);
  rope_table<<<(SEQ * 64) / 256, 256, 0, stream>>>(ct, st);

  // GEMM1 + fused epilogue: grid 512 = 2 blocks/CU x 256, single round
  gemm1s<<<512, 512, 0, stream>>>(xb, wqkvb, q_r, k_r, v_t, ct, st);

  // attn: 256 blocks (1 exact round), 8 waves each
  attn_fwd<<<256, 512, 0, stream>>>(q_r, k_r, v_t, aob);

  // GEMM2: 64x256 tiles -> grid 512 = 2 blocks/CU x 256, single round
  gemm2s<<<512, 256, 0, stream>>>(aob, wprojb, (float*)d_out, b_proj);
}

// Round 12
// 234.937 us; speedup vs baseline: 1.2432x; 1.2432x over previous
//
#include <hip/hip_runtime.h>
#include <hip/hip_bf16.h>

using bf16 = __hip_bfloat16;
typedef __attribute__((ext_vector_type(8))) short bf16x8;
typedef __attribute__((ext_vector_type(4))) float f32x4;
typedef __attribute__((ext_vector_type(16))) float f32x16;
typedef __attribute__((ext_vector_type(4))) unsigned int u32x4;

constexpr int Bz  = 2;
constexpr int SEQ = 2048;
constexpr int DM  = 2048;
constexpr int H   = 16;
constexpr int HD  = 128;
constexpr long MROWS = (long)Bz * SEQ;   // 4096
constexpr int EQ  = 3 * DM;              // 6144
// 1/sqrt(128) * log2(e): fold softmax base-2 conversion into Q scaling
constexpr float QSCALE_L2E = 0.12751743427795914f;

__device__ __forceinline__ float bf2f(bf16 x) { return __bfloat162float(x); }
__device__ __forceinline__ bf16  f2bf(float x) { return __float2bfloat16(x); }

__device__ __forceinline__ float fexp2(float x) {
  float r;
  asm("v_exp_f32 %0, %1" : "=v"(r) : "v"(x));
  return r;
}

template <int N>
__device__ __forceinline__ void waitvm() {
  asm volatile("s_waitcnt vmcnt(%0)" ::"n"(N) : "memory");
}

__device__ __forceinline__ void gl_lds16(const void* g, void* l) {
  __builtin_amdgcn_global_load_lds(
      (const __attribute__((address_space(1))) unsigned int*)g,
      (__attribute__((address_space(3))) unsigned int*)l, 16, 0, 0);
}

// ---------------- merged fp32 -> bf16 converts (x, w_qkv, w_proj in one launch) ----------------
constexpr long NX = MROWS * DM;          // 8388608
constexpr long NW1 = (long)EQ * DM;      // 12582912
constexpr long NW2 = (long)DM * DM;      // 4194304
__global__ void prep_bf16(const float* __restrict__ x, const float* __restrict__ w1,
                          const float* __restrict__ w2, bf16* __restrict__ xb,
                          bf16* __restrict__ w1b, bf16* __restrict__ w2b) {
  long i = ((long)blockIdx.x * 256 + threadIdx.x) * 4;
  const float* src;
  bf16* dst;
  long off;
  if (i < NX) { src = x; dst = xb; off = i; }
  else if (i < NX + NW1) { src = w1; dst = w1b; off = i - NX; }
  else { src = w2; dst = w2b; off = i - NX - NW1; }
  float4 v = *(const float4*)(src + off);
  bf16 tmp[4] = {f2bf(v.x), f2bf(v.y), f2bf(v.z), f2bf(v.w)};
  *(uint2*)(dst + off) = *(uint2*)tmp;
}

// ---------------- RoPE table ----------------
__global__ void rope_table(float* __restrict__ ct, float* __restrict__ st) {
  int idx = blockIdx.x * 256 + threadIdx.x;
  if (idx >= SEQ * 64) return;
  int j = idx & 63, n = idx >> 6;
  double inv = exp(-(double)j / 64.0 * 9.210340371976184); // 10000^{-j/64}
  double a = (double)n * inv;
  ct[idx] = (float)cos(a);
  st[idx] = (float)sin(a);
}

// ============== BM=128 x BN GEMM (R5-verified loop), optional fused QKV epilogue ==============
// 8 waves (2M x 4N), per-wave 64 x (BN/4); NBP = BN/128 phases per K-tile(64).
// Phase bp: {reads, stage 1 chunk of t+1, counted vmcnt, barrier, 16 MFMA (setprio)}.
// FUSE=1 (GEMM1): epilogue writes acc col-major to LDS, then applies RoPE (Q/K) and
// V-transpose directly -> q_r/k_r/v_t. Tile cols = 3 full 128-col head segments.
// acc[i][j] <-> local row (wm+2i)*16 + kq*4 + q, local col (wn+4j)*16 + fr   (VERIFIED vs K-loop)
template <int KTOT, int BN, int NBP, int FUSE>
__global__ __launch_bounds__(512) void gemm128(const bf16* __restrict__ A,
                                               const bf16* __restrict__ Bm,
                                               void* __restrict__ Cv,
                                               const float* __restrict__ bias,
                                               bf16* __restrict__ q_r,
                                               bf16* __restrict__ k_r,
                                               bf16* __restrict__ v_t,
                                               const float* __restrict__ ct,
                                               const float* __restrict__ st,
                                               int M, int Nn) {
  constexpr int NT = KTOT / 64;
  constexpr int ASZ = 128 * 64;            // elems per A buf
  constexpr int BSZ = BN * 64;             // elems per B buf
  __shared__ alignas(16) char smem[2 * ASZ * 2 + 2 * BSZ * 2];
  bf16* lsA = (bf16*)smem;                       // [2][ASZ]
  bf16* lsB = (bf16*)(smem + 2 * ASZ * 2);       // [2][BSZ]

  // bijective XCD swizzle (nwg % 8 == 0 for both grids)
  const int nwg = gridDim.x;
  const int f = blockIdx.x;
  const int wg = (f & 7) * (nwg >> 3) + (f >> 3);
  const int nbm = M >> 7;
  const long am0 = (long)(wg % nbm) * 128;
  const long bn0 = (long)(wg / nbm) * BN;

  const int tid = threadIdx.x;
  const int wv = tid >> 6, ln = tid & 63;
  const int wm = wv & 1, wn = wv >> 1;      // 2 x 4 wave grid
  const int fr = ln & 15, kq = ln >> 4;
  const int sr8 = ln >> 3;                  // staging row within 8-row slab
  const int ss  = ln & 7;                   // staging physical 16B slot

  f32x4 acc[4][2 * NBP] = {};

  auto stageA = [&](int buf, int t) {
#pragma unroll
    for (int ld = 0; ld < 2; ++ld) {
      const int r = ld * 64 + wv * 8 + sr8;
      const int sl = ss ^ (r & 7);
      gl_lds16(A + (am0 + r) * KTOT + t * 64 + sl * 8, lsA + buf * ASZ + (ld * 64 + wv * 8) * 64);
    }
  };
  auto stageB = [&](int buf, int t, int bp) {
#pragma unroll
    for (int ld = 0; ld < 2; ++ld) {
      const int r = bp * 128 + ld * 64 + wv * 8 + sr8;
      const int sl = ss ^ (r & 7);
      gl_lds16(Bm + (bn0 + r) * KTOT + t * 64 + sl * 8,
               lsB + buf * BSZ + (bp * 128 + ld * 64 + wv * 8) * 64);
    }
  };

  // prologue: all chunks of tile 0, full drain
  stageA(0, 0);
#pragma unroll
  for (int bp = 0; bp < NBP; ++bp) stageB(0, 0, bp);
  waitvm<0>();
  __builtin_amdgcn_s_barrier();

#pragma unroll 2
  for (int t = 0; t < NT; ++t) {
    const int cur = t & 1;
    const bool pre = (t + 1 < NT);

    bf16x8 af[8];
#pragma unroll
    for (int bp = 0; bp < NBP; ++bp) {
      if (bp == 0) {
#pragma unroll
        for (int i = 0; i < 4; ++i)
#pragma unroll
          for (int ks = 0; ks < 2; ++ks) {
            const int row = (wm + 2 * i) * 16 + fr;
            const int sl = (ks * 4 + kq) ^ (row & 7);
            af[i * 2 + ks] =
                *(const bf16x8*)((const char*)(lsA + cur * ASZ) + row * 128 + sl * 16);
          }
      }
      bf16x8 bq[4];
#pragma unroll
      for (int jj = 0; jj < 2; ++jj)
#pragma unroll
        for (int ks = 0; ks < 2; ++ks) {
          const int row = (wn + 4 * (2 * bp + jj)) * 16 + fr;
          const int sl = (ks * 4 + kq) ^ (row & 7);
          bq[jj * 2 + ks] =
              *(const bf16x8*)((const char*)(lsB + cur * BSZ) + row * 128 + sl * 16);
        }

      if (pre) {
        if (bp == 0) {
          stageA(cur ^ 1, t + 1);
          stageB(cur ^ 1, t + 1, 0);
          waitvm<2 * NBP>();
        } else if (bp == NBP - 1) {
          stageB(cur ^ 1, t + 1, bp);
          waitvm<2 * (NBP - 1)>();
        } else {
          stageB(cur ^ 1, t + 1, bp);
          waitvm<2 * NBP>();
        }
      } else {
        if (bp == 0) waitvm<(NBP > 2) ? 2 : 0>();
        else waitvm<0>();
      }
      __builtin_amdgcn_s_barrier();

      __builtin_amdgcn_s_setprio(1);
#pragma unroll
      for (int i = 0; i < 4; ++i)
#pragma unroll
        for (int jj = 0; jj < 2; ++jj)
#pragma unroll
          for (int ks = 0; ks < 2; ++ks)
            acc[i][2 * bp + jj] = __builtin_amdgcn_mfma_f32_16x16x32_bf16(
                af[i * 2 + ks], bq[jj * 2 + ks], acc[i][2 * bp + jj], 0, 0, 0);
      __builtin_amdgcn_s_setprio(0);
    }
  }

  if constexpr (FUSE) {
    // ---- fused epilogue: acc -> LDS col-major [384 cols][136 rows], then RoPE / V-transpose
    static_assert(BN == 384, "fused epilogue assumes 3 head segments per tile");
    bf16* eb = (bf16*)smem;   // 384*136*2 = 104448 B <= 131072
    __syncthreads();          // drain all waves' K-loop ds_reads before overwriting LDS
#pragma unroll
    for (int i = 0; i < 4; ++i) {
      const int r0 = (wm + 2 * i) * 16 + kq * 4;          // local row (matches K-loop mapping)
#pragma unroll
      for (int j = 0; j < 2 * NBP; ++j) {
        const int c = (wn + 4 * j) * 16 + fr;             // local col (matches K-loop mapping)
        bf16 t4[4];
#pragma unroll
        for (int q = 0; q < 4; ++q) t4[q] = f2bf(acc[i][j][q]);
        *(uint2*)(eb + c * 136 + r0) = *(uint2*)t4;
      }
    }
    __syncthreads();
    const int bb = (int)(am0 >> 11);          // batch (tile rows stay within one b)
    const int nbase = (int)(am0 & 2047);
#pragma unroll
    for (int cb = 0; cb < 3; ++cb) {
      const int gc = (int)bn0 + cb * 128;
      const int seg = gc >> 11;               // 0=Q 1=K 2=V
      const long bh = bb * 16 + ((gc & 2047) >> 7);
      if (seg < 2) {
        bf16* dst = (seg == 0) ? q_r : k_r;
        const float qs = (seg == 0) ? QSCALE_L2E : 1.0f;
        for (int itx = 0; itx < 16; ++itx) {
          const int idx = itx * 512 + tid;
          const int r = idx >> 6, j = idx & 63;
          const int n = nbase + r;
          const float v1 = bf2f(eb[(cb * 128 + j) * 136 + r]);
          const float v2 = bf2f(eb[(cb * 128 + j + 64) * 136 + r]);
          const float cc = ct[n * 64 + j], sv = st[n * 64 + j];
          const long ob = (bh * SEQ + n) * HD + j;
          dst[ob]      = f2bf((v1 * cc - v2 * sv) * qs);
          dst[ob + 64] = f2bf((v1 * sv + v2 * cc) * qs);
        }
      } else {
        for (int itx = 0; itx < 4; ++itx) {
          const int idx = itx * 512 + tid;
          const int d = idx >> 4, n8 = (idx & 15) * 8;
          bf16x8 v = *(const bf16x8*)(eb + (cb * 128 + d) * 136 + n8);
          *(bf16x8*)(v_t + (bh * HD + d) * SEQ + nbase + n8) = v;
        }
      }
    }
  } else {
    // ---- plain epilogue: f32 + bias
#pragma unroll
    for (int i = 0; i < 4; ++i) {
      const long row0 = am0 + (wm + 2 * i) * 16 + kq * 4;
#pragma unroll
      for (int j = 0; j < 2 * NBP; ++j) {
        const long col = bn0 + (wn + 4 * j) * 16 + fr;
        const float bv = bias ? bias[col] : 0.f;
#pragma unroll
        for (int q = 0; q < 4; ++q) {
          const float v = acc[i][j][q] + bv;
          ((float*)Cv)[(row0 + q) * Nn + col] = v;
        }
      }
    }
  }
}

// ---------------- Flash attention: 8 waves, swapped-QK^T 32x32, defer-max ----------------
__global__ __launch_bounds__(512, 2) void attn_fwd(const bf16* __restrict__ q_r,
                                                   const bf16* __restrict__ k_r,
                                                   const bf16* __restrict__ v_t,
                                                   bf16* __restrict__ ao) {
  __shared__ alignas(16) char lds[69632];

  // XCD grouping: 256 blocks; XCD x hosts bh in [4x, 4x+4) (4MB KV = one L2)
  const int flat = blockIdx.x;                       // 0..255
  const int bh = (flat & 7) * 4 + (flat >> 6);
  const int qt = (flat >> 3) & 7;
  const int b = bh >> 4, h = bh & 15;

  const int wv = threadIdx.x >> 6, ln = threadIdx.x & 63;
  const int lh = ln >> 5;
  const int lq = ln & 31;
  const int q0 = qt * 256 + wv * 32;

  bf16x8 aq[8];
  {
    const char* qbase = (const char*)(q_r + ((long)bh * SEQ + q0 + lq) * HD);
#pragma unroll
    for (int ks = 0; ks < 8; ++ks)
      aq[ks] = *(const bf16x8*)(qbase + ks * 32 + lh * 16);
  }

  f32x16 oacc[4] = {};
  float mrow = -1e30f, lsum = 0.f;

  auto stage = [&](int buf, int t) {
    char* kb = lds + buf * 16384;
    char* vb = lds + 32768 + buf * 16384;
#pragma unroll
    for (int cc = 0; cc < 4; ++cc) {
      const int chunk = wv * 4 + cc;          // 0..15 K, 16..31 V
      if (chunk < 16) {
        const int r = chunk * 4 + (ln >> 4);
        const char* src = (const char*)k_r + ((long)bh * SEQ + t * 64 + r) * 256 +
                          (((ln & 15) ^ (r & 15)) << 4);
        gl_lds16(src, kb + chunk * 1024);
      } else {
        const int c2 = chunk - 16;
        const int r = c2 * 8 + (ln >> 3);
        const char* src = (const char*)v_t + ((long)bh * HD + r) * (SEQ * 2) + t * 128 +
                          (((ln & 7) ^ (r & 7)) << 4);
        gl_lds16(src, vb + c2 * 1024);
      }
    }
  };

  stage(0, 0);
  __syncthreads();

  for (int t = 0; t < SEQ / 64; ++t) {
    const int cur = t & 1;
    if (t + 1 < SEQ / 64) stage(cur ^ 1, t + 1);
    const char* kb = lds + cur * 16384;
    const char* vb = lds + 32768 + cur * 16384;

    f32x16 sacc[2] = {};
    __builtin_amdgcn_s_setprio(1);
#pragma unroll
    for (int kvs = 0; kvs < 2; ++kvs) {
      const int kv = kvs * 32 + lq;
#pragma unroll
      for (int ks = 0; ks < 8; ++ks) {
        bf16x8 kf = *(const bf16x8*)(kb + kv * 256 + ((((ks << 1) | lh) ^ (kv & 15)) << 4));
        sacc[kvs] = __builtin_amdgcn_mfma_f32_32x32x16_bf16(kf, aq[ks], sacc[kvs], 0, 0, 0);
      }
    }
    __builtin_amdgcn_s_setprio(0);

    float mx = sacc[0][0];
#pragma unroll
    for (int r = 1; r < 16; ++r) mx = fmaxf(mx, sacc[0][r]);
#pragma unroll
    for (int r = 0; r < 16; ++r) mx = fmaxf(mx, sacc[1][r]);
    mx = fmaxf(mx, __shfl_xor(mx, 32, 64));

    // defer-max (T13)
    if (!__all(mx - mrow <= 8.0f)) {
      const float mn = fmaxf(mrow, mx);
      const float scale = fexp2(mrow - mn);
      mrow = mn;
      lsum *= scale;
#pragma unroll
      for (int dt = 0; dt < 4; ++dt) oacc[dt] *= scale;
    }
    float psum = 0.f;
#pragma unroll
    for (int k2 = 0; k2 < 2; ++k2)
#pragma unroll
      for (int r = 0; r < 16; ++r) {
        const float pv = fexp2(sacc[k2][r] - mrow);
        sacc[k2][r] = pv;
        psum += pv;
      }
    psum += __shfl_xor(psum, 32, 64);
    lsum += psum;

    bf16x8 pfrag[4];
#pragma unroll
    for (int k2 = 0; k2 < 2; ++k2) {
      unsigned int pk[8];
#pragma unroll
      for (int i = 0; i < 8; ++i) {
        unsigned int lo = __bfloat16_as_ushort(f2bf(sacc[k2][2 * i]));
        unsigned int hi = __bfloat16_as_ushort(f2bf(sacc[k2][2 * i + 1]));
        pk[i] = lo | (hi << 16);
      }
#pragma unroll
      for (int fb = 0; fb < 2; ++fb) {
        const unsigned int a0 = pk[fb * 4 + 0], a1 = pk[fb * 4 + 1];
        const unsigned int b0 = pk[fb * 4 + 2], b1 = pk[fb * 4 + 3];
        const unsigned int sb0 = __shfl_xor(b0, 32, 64);
        const unsigned int sb1 = __shfl_xor(b1, 32, 64);
        const unsigned int sa0 = __shfl_xor(a0, 32, 64);
        const unsigned int sa1 = __shfl_xor(a1, 32, 64);
        u32x4 wvec;
        wvec.x = lh ? sb0 : a0;
        wvec.y = lh ? sb1 : a1;
        wvec.z = lh ? b0 : sa0;
        wvec.w = lh ? b1 : sa1;
        pfrag[k2 * 2 + fb] = __builtin_bit_cast(bf16x8, wvec);
      }
    }

    __builtin_amdgcn_s_setprio(1);
#pragma unroll
    for (int dt = 0; dt < 4; ++dt) {
      const int d = dt * 32 + lq;
#pragma unroll
      for (int kk = 0; kk < 4; ++kk) {
        bf16x8 vf = *(const bf16x8*)(vb + d * 128 + ((((kk << 1) | lh) ^ (d & 7)) << 4));
        oacc[dt] = __builtin_amdgcn_mfma_f32_32x32x16_bf16(vf, pfrag[kk], oacc[dt], 0, 0, 0);
      }
    }
    __builtin_amdgcn_s_setprio(0);
    __syncthreads();
  }

  // epilogue: O^T -> LDS transpose -> coalesced store
  const float inv = 1.0f / lsum;
  bf16* ob = (bf16*)lds;
  const int qloc = wv * 32 + lq;
#pragma unroll
  for (int dt = 0; dt < 4; ++dt)
#pragma unroll
    for (int r = 0; r < 16; ++r) {
      const int d = dt * 32 + (r & 3) + 8 * (r >> 2) + 4 * lh;
      ob[qloc * 132 + d] = f2bf(oacc[dt][r] * inv);
    }
#pragma unroll
  for (int it = 0; it < 8; ++it) {
    const int c = it * 64 + ln;
    const int qq = c >> 4, dc = c & 15;
    const char* srcp = (const char*)ob + (wv * 32 + qq) * 264 + dc * 16;
    uint2 v0 = *(const uint2*)srcp;
    uint2 v1 = *(const uint2*)(srcp + 8);
    uint4 outv;
    outv.x = v0.x; outv.y = v0.y; outv.z = v1.x; outv.w = v1.y;
    *(uint4*)((char*)(ao + ((long)b * SEQ + qt * 256 + wv * 32 + qq) * DM + h * 128) + dc * 16) = outv;
  }
}

// ---------------- launch ----------------
extern "C" void kernel_launch(void* const* d_in, const int* in_sizes, int n_in,
                              void* d_out, int out_size, void* d_ws, size_t ws_size,
                              hipStream_t stream) {
  const float* x      = (const float*)d_in[0];
  const float* w_qkv  = (const float*)d_in[1];
  const float* w_proj = (const float*)d_in[2];
  const float* b_proj = (const float*)d_in[3];

  char* ws = (char*)d_ws;
  size_t off = 0;
  auto alloc = [&](size_t bytes) {
    void* p = ws + off;
    off += (bytes + 255) & ~(size_t)255;
    return p;
  };
  bf16* xb     = (bf16*)alloc((size_t)MROWS * DM * 2);
  bf16* wqkvb  = (bf16*)alloc((size_t)EQ * DM * 2);
  bf16* wprojb = (bf16*)alloc((size_t)DM * DM * 2);
  bf16* q_r    = (bf16*)alloc((size_t)Bz * H * SEQ * HD * 2);
  bf16* k_r    = (bf16*)alloc((size_t)Bz * H * SEQ * HD * 2);
  bf16* v_t    = (bf16*)alloc((size_t)Bz * H * SEQ * HD * 2);
  bf16* aob    = (bf16*)alloc((size_t)MROWS * DM * 2);
  float* ct    = (float*)alloc((size_t)SEQ * 64 * 4);
  float* st    = (float*)alloc((size_t)SEQ * 64 * 4);

  // merged converts: (NX+NW1+NW2)/4/256 = 24576 blocks exactly
  prep_bf16<<<(int)((NX + NW1 + NW2) / 4 / 256), 256, 0, stream>>>(
      x, w_qkv, w_proj, xb, wqkvb, wprojb);
  rope_table<<<(SEQ * 64) / 256, 256, 0, stream>>>(ct, st);

  // GEMM1 + fused RoPE/reshape/V-transpose epilogue: grid 512 = 2 exact rounds
  gemm128<2048, 384, 3, 1><<<(int)(MROWS / 128) * (EQ / 384), 512, 0, stream>>>(
      xb, wqkvb, nullptr, nullptr, q_r, k_r, v_t, ct, st, (int)MROWS, EQ);

  // attn: 256 blocks (1 exact round), 8 waves each
  attn_fwd<<<256, 512, 0, stream>>>(q_r, k_r, v_t, aob);

  // GEMM2: 4096x2048x2048, BM=128 BN=256 -> grid 256 = 1 exact round
  gemm128<2048, 256, 2, 0><<<(int)(MROWS / 128) * (DM / 256), 512, 0, stream>>>(
      aob, wprojb, d_out, b_proj, nullptr, nullptr, nullptr, nullptr, nullptr,
      (int)MROWS, DM);
}